// Round 7
// baseline (4996.311 us; speedup 1.0000x reference)
//
#include <hip/hip_runtime.h>
#include <hip/hip_bf16.h>
#include <cstdint>

// ---------------------------------------------------------------------------
// BiLSTM: x[2048,1024] -> bidirectional LSTM (H=1024) -> FC to 1000 classes.
//   1. convert_all: fp32 -> f16 copies of x, W_ih_f, W_ih_b, fc_W
//   2. gemm_f16<0>: x_proj_d = x_d @ W_ih_d^T + b_ih + b_hh, stored
//      TRANSPOSED as [t][unit*4+gate] so the recurrence's per-step xp
//      prefetch is ONE dwordx2 (R11's 4 scattered loads polluted the
//      vmcnt FIFO and cost ~1 RTT/step).
//   3. lstm_rec R12: R10 skeleton (atomicExch publish, verified) +
//      counted depth-2 probe pipeline with an exact FIFO ledger:
//      per-wave queue at poll = [exch, hist_st, A, XP, B] -> uniform
//      s_waitcnt vmcnt(1) at every check (first check retires
//      exch/st/A/XP ~ 1 RTT; steady state alternates A/B at RTT/2).
//      NO drain on hit: sibling probe stays in flight; its registers kept
//      live to a vmcnt(0)+asm-sink at END of compute (~free by then).
//      Raw barrier (lgkmcnt(0)+s_barrier) so the compiler can't insert
//      vmcnt(0) at the barrier. Fallback to the proven R10 atomic poll
//      after 32 fast iterations (bounded downside ~ R10; probe visibility
//      itself was runtime-proven in R11).
//      Kept (verified): gates-per-lane + DPP reduce, exchange publish,
//      epoch-salted tags, bailouts.
//   4. gemm_f16<1>: out = h_hist @ fc_W^T + fc_b
// ---------------------------------------------------------------------------

typedef __fp16 h2 __attribute__((ext_vector_type(2)));
typedef __fp16 h8 __attribute__((ext_vector_type(8)));
typedef float f4 __attribute__((ext_vector_type(4)));
typedef unsigned int u32x4 __attribute__((ext_vector_type(4)));
typedef unsigned long long u64;

#define T_LEN 2048

static __device__ __forceinline__ unsigned int packh2(float a, float b) {
  h2 r = __builtin_amdgcn_cvt_pkrtz(a, b);
  return __builtin_bit_cast(unsigned int, r);
}
static __device__ __forceinline__ float fdot2u(unsigned int a, unsigned int b, float c) {
  return __builtin_amdgcn_fdot2(__builtin_bit_cast(h2, a), __builtin_bit_cast(h2, b), c, false);
}
static __device__ __forceinline__ float sigmoidf_(float x) {
  return 1.f / (1.f + __expf(-x));
}
static __device__ __forceinline__ float tanhf_(float x) {
  float e = __expf(-2.f * fabsf(x));
  float r = (1.f - e) / (1.f + e);
  return copysignf(r, x);
}
static __device__ __forceinline__ u64 aload(const u64* p) {
  return __hip_atomic_load(p, __ATOMIC_RELAXED, __HIP_MEMORY_SCOPE_AGENT);
}

// 16-lane (DPP-row) sum reduction: xor1, xor2 (quad_perm), row_half_mirror,
// row_mirror. All 16 lanes of the row end with the row sum. (R7/R10-verified.)
#define DPP_ADD1(v, CTRL)                                                      \
  v += __builtin_bit_cast(                                                     \
      float, __builtin_amdgcn_update_dpp(0, __builtin_bit_cast(int, v), CTRL,  \
                                         0xf, 0xf, true))
#define DPP_ROUND(CTRL)                                                        \
  DPP_ADD1(acc0, CTRL);                                                        \
  DPP_ADD1(acc1, CTRL);                                                        \
  DPP_ADD1(acc2, CTRL);                                                        \
  DPP_ADD1(acc3, CTRL)

// ---------------------------------------------------------------------------
__global__ void convert_all(const float* __restrict__ x, const float* __restrict__ wf,
                            const float* __restrict__ wb, const float* __restrict__ fcw,
                            _Float16* __restrict__ xf, _Float16* __restrict__ wff,
                            _Float16* __restrict__ wbf, _Float16* __restrict__ fcwf) {
  const size_t SX = 2097152, SW = 4194304, SFC = 2097152;
  size_t i = (size_t)blockIdx.x * 256 + threadIdx.x;
  if (i < SX) {
    xf[i] = (_Float16)x[i];
  } else if (i < SX + SW) {
    size_t j = i - SX; wff[j] = (_Float16)wf[j];
  } else if (i < SX + 2 * SW) {
    size_t j = i - SX - SW; wbf[j] = (_Float16)wb[j];
  } else if (i < SX + 2 * SW + SFC) {
    size_t j = i - SX - 2 * SW;
    int row = (int)(j >> 11), col = (int)(j & 2047);
    fcwf[j] = (row < 1000) ? (_Float16)fcw[(size_t)row * 2048 + col] : (_Float16)0.f;
  }
}

// epoch bump + seed gen-0 tags (payload h=0, tag=epoch<<12).
__global__ void init_state(u64* __restrict__ hc, unsigned* __restrict__ ep) {
  __shared__ unsigned sbs;
  if (threadIdx.x == 0) sbs = atomicAdd(ep, 1u) << 12;
  __syncthreads();
  u64 v = (u64)sbs;
  for (int i = threadIdx.x; i < 2048; i += 256)
    __hip_atomic_store(&hc[i], v, __ATOMIC_RELAXED, __HIP_MEMORY_SCOPE_AGENT);
}

// ---------------------------------------------------------------------------
// f16 GEMM, 128x128 tile, BK=64 (verified R2/R3/R4).
// MODE 0: store x_proj TRANSPOSED: col = unit*4 + gate  (n = gate*1024+unit)
// ---------------------------------------------------------------------------
#define LSTR 80

template <int MODE>
__global__ __launch_bounds__(256, 2) void gemm_f16(
    const _Float16* __restrict__ A, const _Float16* __restrict__ B,
    const float* __restrict__ bias1, const float* __restrict__ bias2,
    void* __restrict__ Cout, int M, int N, int K, int nout, int rev) {
  __shared__ _Float16 As[128 * LSTR];
  __shared__ _Float16 Bs[128 * LSTR];

  const int tid = threadIdx.x;
  const int ntn = N >> 7;
  const int tm = blockIdx.x / ntn, tn = blockIdx.x % ntn;
  const int wid = tid >> 6, lane = tid & 63;
  const int wr = wid >> 1, wc = wid & 1;
  const int quad = lane >> 4, l16 = lane & 15;

  const int srow = tid >> 1, seg = tid & 1;
  const int arow = rev ? (M - 1 - (tm * 128 + srow)) : (tm * 128 + srow);
  const int brow = tn * 128 + srow;

  f4 acc[4][4];
#pragma unroll
  for (int i = 0; i < 4; ++i)
#pragma unroll
    for (int j = 0; j < 4; ++j) acc[i][j] = (f4)0.f;

  for (int k0 = 0; k0 < K; k0 += 64) {
    uint4 va[4], vb[4];
    const uint4* gpa = (const uint4*)(A + (size_t)arow * K + k0 + seg * 32);
    const uint4* gpb = (const uint4*)(B + (size_t)brow * K + k0 + seg * 32);
#pragma unroll
    for (int c = 0; c < 4; ++c) va[c] = gpa[c];
#pragma unroll
    for (int c = 0; c < 4; ++c) vb[c] = gpb[c];

    __syncthreads();
    uint4* lpa = (uint4*)&As[srow * LSTR + seg * 32];
    uint4* lpb = (uint4*)&Bs[srow * LSTR + seg * 32];
#pragma unroll
    for (int c = 0; c < 4; ++c) lpa[c] = va[c];
#pragma unroll
    for (int c = 0; c < 4; ++c) lpb[c] = vb[c];
    __syncthreads();

#pragma unroll
    for (int kk = 0; kk < 64; kk += 32) {
      h8 af[4], bf[4];
#pragma unroll
      for (int i = 0; i < 4; ++i) {
        int m = wr * 64 + i * 16 + l16;
        af[i] = *(const h8*)&As[m * LSTR + kk + quad * 8];
        int n = wc * 64 + i * 16 + l16;
        bf[i] = *(const h8*)&Bs[n * LSTR + kk + quad * 8];
      }
#pragma unroll
      for (int i = 0; i < 4; ++i)
#pragma unroll
        for (int j = 0; j < 4; ++j)
          acc[i][j] = __builtin_amdgcn_mfma_f32_16x16x32_f16(af[i], bf[j], acc[i][j], 0, 0, 0);
    }
  }

  const int cm0 = tm * 128 + wr * 64, cn0 = tn * 128 + wc * 64;
#pragma unroll
  for (int i = 0; i < 4; ++i) {
#pragma unroll
    for (int j = 0; j < 4; ++j) {
      int n = cn0 + j * 16 + l16;
#pragma unroll
      for (int r = 0; r < 4; ++r) {
        int m = cm0 + i * 16 + quad * 4 + r;
        float v = acc[i][j][r];
        if (MODE == 0) {
          v += bias1[n] + bias2[n];
          int cc = ((n & 1023) << 2) | (n >> 10);  // unit*4 + gate
          ((_Float16*)Cout)[(size_t)m * N + cc] = (_Float16)v;
        } else {
          if (n < nout) ((float*)Cout)[(size_t)m * nout + n] = v + bias1[n];
        }
      }
    }
  }
}

// ---------------------------------------------------------------------------
// Persistent BiLSTM recurrence, R12.
// 128 blocks x 256 thr (4 waves), 1 block/CU. blk<64 fwd else bwd. Block
// owns 16 units j0..j0+15 = one 64B hc line. Wave wv owns units 4wv+rr
// (rr=lane>>4); lane computes the 4 GATE dots of its unit over k-slice
// kq*64..+63. hc: [buf][dir][512] u64; word = [pay32|tag32], tag=(ep<<12)+gen.
// Publish: lanes 0-1/wave atomicExch (R10). Poll: depth-2 dwordx4 sc0 sc1
// probe pipeline, uniform vmcnt(1) via exact FIFO ledger (see header),
// no-drain-on-hit (sink at end-of-compute vmcnt(0)), raw lgkm barrier,
// 32-iter fallback to the R10 atomic poll.
// ---------------------------------------------------------------------------
__global__ __launch_bounds__(256, 1) void lstm_rec(
    const float* __restrict__ Whh_f, const float* __restrict__ Whh_b,
    const _Float16* __restrict__ xp,   // [2][2048][4096] (unit*4+gate layout)
    u64* __restrict__ hc,              // [2][2][512] agent-scope
    unsigned* __restrict__ ep,         // epoch counter (post-incremented)
    _Float16* __restrict__ hhist) {    // [2048][2048]
  const int tid = threadIdx.x;
  const int blk = blockIdx.x;
  const int dir = blk >> 6;
  const int ib = blk & 63;
  const int j0 = ib * 16;
  const int wv = tid >> 6;
  const int l = tid & 63;
  const int rr = l >> 4;     // unit replica 0..3 (DPP row)
  const int kq = l & 15;     // 16 k-slices of 64
  const int wrow_u = j0 + 4 * wv + rr;  // unit index within [0,1024)

  const unsigned SB =
      (__hip_atomic_load(ep, __ATOMIC_RELAXED, __HIP_MEMORY_SCOPE_AGENT) - 1u) << 12;

  const float* Whh = dir ? Whh_b : Whh_f;
  const _Float16* xpd = xp + (size_t)dir * (2048u * 4096u);

  __shared__ unsigned int lds_h[2][16 * 36];  // [buf][seg stride 36]

  // one-time: W_hh[g*1024 + wrow_u][kq*64 .. +63] -> f16 regs, g = gate 0..3
  unsigned int w[4][32];
#pragma unroll
  for (int g = 0; g < 4; ++g) {
    const float* wp = Whh + (size_t)(g * 1024 + wrow_u) * 1024 + kq * 64;
#pragma unroll
    for (int i = 0; i < 16; ++i) {
      float4 v = ((const float4*)wp)[i];
      w[g][2 * i] = packh2(v.x, v.y);
      w[g][2 * i + 1] = packh2(v.z, v.w);
    }
  }

  float c = 0.f;  // cell state for unit wrow_u (replicated across 16 lanes)

  // x_proj for t=0: 4 gate preacts of unit wrow_u (contiguous, new layout)
  float xf0, xf1, xf2, xf3;
  {
    uint2 xv = *(const uint2*)(xpd + (size_t)wrow_u * 4);
    h2 xa = __builtin_bit_cast(h2, xv.x);
    h2 xb = __builtin_bit_cast(h2, xv.y);
    xf0 = (float)xa[0]; xf1 = (float)xa[1];
    xf2 = (float)xb[0]; xf3 = (float)xb[1];
  }

  for (int t = 0; t < T_LEN; ++t) {
    const int buf = t & 1;
    const unsigned exp0 = SB + (unsigned)t;
    const u64* src = hc + (((size_t)buf * 2 + dir) * 512 + 2 * tid);
    int tnx = (t + 1 < T_LEN) ? t + 1 : t;
    const _Float16* xr = xpd + (size_t)tnx * 4096 + (size_t)wrow_u * 4;

    // ---- depth-2 probe pipeline. Per-wave vmcnt FIFO at this point:
    // [exch, hist_st] (prev step, ~retired) then we append A, XP, B.
    // vmcnt(1) at every check retires everything up to the checked probe.
    u32x4 A, Bv;
    uint2 XP;
    asm volatile("global_load_dwordx4 %0, %1, off sc0 sc1"
                 : "=v"(A) : "v"(src) : "memory");
    asm volatile("global_load_dwordx2 %0, %1, off"
                 : "=v"(XP) : "v"(xr) : "memory");
    asm volatile("global_load_dwordx4 %0, %1, off sc0 sc1"
                 : "=v"(Bv) : "v"(src) : "memory");

    unsigned d0, d1;
    {
      int cnt = 0;
      for (;;) {
        asm volatile("s_waitcnt vmcnt(1)" ::: "memory");
        __builtin_amdgcn_sched_barrier(0);
        if (A[0] == exp0 && A[2] == exp0) { d0 = A[1]; d1 = A[3]; break; }
        asm volatile("global_load_dwordx4 %0, %1, off sc0 sc1"
                     : "=v"(A) : "v"(src) : "memory");
        asm volatile("s_waitcnt vmcnt(1)" ::: "memory");
        __builtin_amdgcn_sched_barrier(0);
        if (Bv[0] == exp0 && Bv[2] == exp0) { d0 = Bv[1]; d1 = Bv[3]; break; }
        asm volatile("global_load_dwordx4 %0, %1, off sc0 sc1"
                     : "=v"(Bv) : "v"(src) : "memory");
        if (++cnt > 32) {
          // fallback: proven R10 atomic poll (correct regardless of probe
          // behavior; compiler inserts its own conservative waits)
          u64 a = aload(&src[0]), b = aload(&src[1]);
          int c2 = 0;
          while ((unsigned)a != exp0 || (unsigned)b != exp0) {
            if (++c2 > (1 << 12)) break;  // bailout: never hang
            a = aload(&src[0]);
            b = aload(&src[1]);
          }
          d0 = (unsigned)(a >> 32);
          d1 = (unsigned)(b >> 32);
          break;
        }
      }
    }

    // xp for t+1: XP retired before any loop exit (vmcnt(1) ledger).
    h2 xa = __builtin_bit_cast(h2, XP.x);
    h2 xb = __builtin_bit_cast(h2, XP.y);
    float nf0 = (float)xa[0], nf1 = (float)xa[1];
    float nf2 = (float)xb[0], nf3 = (float)xb[1];

    // stage h payload: dwords 2tid,2tid+1 -> seg tid>>4, offset 2*(tid&15)
    *(uint2*)&lds_h[buf][(tid >> 4) * 36 + 2 * (tid & 15)] = make_uint2(d0, d1);
    // raw barrier: LDS ordering only (no compiler vmcnt(0) -> the in-flight
    // sibling probe stays outstanding across it)
    asm volatile("s_waitcnt lgkmcnt(0)\n\ts_barrier" ::: "memory");

    // ---- dot: 4 gates x 64-elem slice; 8 ds_read_b128, 128 fdot2 ----
    float acc0 = 0.f, acc1 = 0.f, acc2 = 0.f, acc3 = 0.f;
    const uint4* hp = (const uint4*)&lds_h[buf][kq * 36];
#pragma unroll
    for (int i = 0; i < 8; ++i) {
      uint4 hv = hp[i];
      acc0 = fdot2u(w[0][4 * i + 0], hv.x, acc0);
      acc0 = fdot2u(w[0][4 * i + 1], hv.y, acc0);
      acc0 = fdot2u(w[0][4 * i + 2], hv.z, acc0);
      acc0 = fdot2u(w[0][4 * i + 3], hv.w, acc0);
      acc1 = fdot2u(w[1][4 * i + 0], hv.x, acc1);
      acc1 = fdot2u(w[1][4 * i + 1], hv.y, acc1);
      acc1 = fdot2u(w[1][4 * i + 2], hv.z, acc1);
      acc1 = fdot2u(w[1][4 * i + 3], hv.w, acc1);
      acc2 = fdot2u(w[2][4 * i + 0], hv.x, acc2);
      acc2 = fdot2u(w[2][4 * i + 1], hv.y, acc2);
      acc2 = fdot2u(w[2][4 * i + 2], hv.z, acc2);
      acc2 = fdot2u(w[2][4 * i + 3], hv.w, acc2);
      acc3 = fdot2u(w[3][4 * i + 0], hv.x, acc3);
      acc3 = fdot2u(w[3][4 * i + 1], hv.y, acc3);
      acc3 = fdot2u(w[3][4 * i + 2], hv.z, acc3);
      acc3 = fdot2u(w[3][4 * i + 3], hv.w, acc3);
    }
    // 16-lane reduce via DPP (VALU-only): xor1, xor2, 8-mirror, 16-mirror
    DPP_ROUND(0xB1);   // quad_perm {1,0,3,2}
    DPP_ROUND(0x4E);   // quad_perm {2,3,0,1}
    DPP_ROUND(0x141);  // row_half_mirror
    DPP_ROUND(0x140);  // row_mirror

    // lane now holds all 4 gate preacts of unit wrow_u directly
    float ii = sigmoidf_(acc0 + xf0);
    float ff = sigmoidf_(acc1 + xf1);
    float g_ = tanhf_(acc2 + xf2);
    float oo = sigmoidf_(acc3 + xf3);
    c = ff * c + ii * g_;
    float h = oo * tanhf_(c);  // replicated over 16 lanes of row rr

    // pack pairs: all lanes 0-15 end holding pk=(h0,h1), pko=(h2,h3)
    float hx = __shfl_xor(h, 16, 64);
    unsigned pk = packh2(h, hx);
    unsigned pko = (unsigned)__shfl_xor((int)pk, 32, 64);

    // late drain + liveness sink: the sibling probe (issued ~RTT/2 before
    // detection) is long done by now -> ~free. Keeps A/Bv registers
    // reserved until no in-flight load can write them.
    asm volatile("s_waitcnt vmcnt(0)" : : "v"(A), "v"(Bv) : "memory");
    __builtin_amdgcn_sched_barrier(0);

    const unsigned tg = SB + (unsigned)(t + 1);
    const int slot = (t + 1) & 1;
    // publish: lanes 0-1 of each wave exchange their wave's 2 words in ONE
    // wave instruction (R10-verified).
    if (l < 2) {
      u64 v = (l == 0) ? (((u64)pk << 32) | tg) : (((u64)pko << 32) | tg);
      u64* dst = hc + (((size_t)slot * 2 + dir) * 512 +
                       (size_t)(ib * 8 + 2 * wv + l));
      (void)__hip_atomic_exchange(dst, v, __ATOMIC_RELAXED,
                                  __HIP_MEMORY_SCOPE_AGENT);
      // hhist AFTER publish (off the critical sync path): 2 lanes x 4B
      int tout = dir ? (T_LEN - 1 - t) : t;
      *(unsigned*)&hhist[(size_t)tout * 2048 +
                         (size_t)(dir * 1024 + j0 + 4 * wv + 2 * l)] =
          (l == 0) ? pk : pko;
    }

    // next-step xp (loaded via XP above)
    xf0 = nf0; xf1 = nf1; xf2 = nf2; xf3 = nf3;
  }
}

// ---------------------------------------------------------------------------
extern "C" void kernel_launch(void* const* d_in, const int* in_sizes, int n_in,
                              void* d_out, int out_size, void* d_ws, size_t ws_size,
                              hipStream_t stream) {
  (void)in_sizes; (void)n_in; (void)out_size; (void)ws_size;
  const float* x     = (const float*)d_in[0];
  const float* Wih_f = (const float*)d_in[1];
  const float* Whh_f = (const float*)d_in[2];
  const float* bih_f = (const float*)d_in[3];
  const float* bhh_f = (const float*)d_in[4];
  const float* Wih_b = (const float*)d_in[5];
  const float* Whh_b = (const float*)d_in[6];
  const float* bih_b = (const float*)d_in[7];
  const float* bhh_b = (const float*)d_in[8];
  const float* fcW   = (const float*)d_in[9];
  const float* fcb   = (const float*)d_in[10];

  char* ws = (char*)d_ws;
  _Float16* xf16   = (_Float16*)(ws + 0);
  _Float16* wih16f = (_Float16*)(ws + 4194304);
  _Float16* wih16b = (_Float16*)(ws + 12582912);
  _Float16* fcw16  = (_Float16*)(ws + 20971520);
  _Float16* xp16   = (_Float16*)(ws + 25165824);   // [2][2048][4096]
  _Float16* hhist  = (_Float16*)(ws + 58720256);   // [2048][2048]
  u64*      hc     = (u64*)     (ws + 67108864);   // [2][2][512]
  unsigned* epoch  = (unsigned*)(ws + 67141632);   // epoch counter

  const size_t SX = 2097152, SW = 4194304, SFC = 2097152;
  const size_t total_cvt = SX + 2 * SW + SFC;

  convert_all<<<dim3((unsigned)((total_cvt + 255) / 256)), 256, 0, stream>>>(
      x, Wih_f, Wih_b, fcW, xf16, wih16f, wih16b, fcw16);
  init_state<<<1, 256, 0, stream>>>(hc, epoch);

  gemm_f16<0><<<dim3(512), 256, 0, stream>>>(xf16, wih16f, bih_f, bhh_f,
                                             (void*)xp16, 2048, 4096, 1024, 4096, 0);
  gemm_f16<0><<<dim3(512), 256, 0, stream>>>(xf16, wih16b, bih_b, bhh_b,
                                             (void*)(xp16 + (size_t)2048 * 4096),
                                             2048, 4096, 1024, 4096, 1);

  lstm_rec<<<dim3(128), 256, 0, stream>>>(Whh_f, Whh_b, xp16, hc, epoch, hhist);

  gemm_f16<1><<<dim3(128), 256, 0, stream>>>(hhist, fcw16, fcb, nullptr,
                                             d_out, 2048, 1024, 2048, 1000, 0);
}

// Round 8
// 3327.161 us; speedup vs baseline: 1.5017x; 1.5017x over previous
//
#include <hip/hip_runtime.h>
#include <hip/hip_bf16.h>
#include <cstdint>

// ---------------------------------------------------------------------------
// BiLSTM: x[2048,1024] -> bidirectional LSTM (H=1024) -> FC to 1000 classes.
//   1. convert_all: fp32 -> f16 copies of x, W_ih_f, W_ih_b, fc_W
//   2. gemm_f16<0>: x_proj_d = x_d @ W_ih_d^T + b_ih + b_hh   (f16 MFMA)
//   3. lstm_rec R13 = R10 (best verified: 2951us) + publish-lane split.
//      Protocol (verified R10): single-outstanding agent atomic poll;
//      publish via atomicExch from ONE wave instruction. Depth-2/pipelined
//      polling retired after 3 falsifications (R8/R11/R12): two outstanding
//      probes to the same address coalesce at the MSHR/TCC -> no extra
//      sampling, only overhead. R13 micro: lanes 0 AND 32 publish (pk is
//      already correct on both after one shfl_xor(16)), moving the
//      shfl_xor(32) off the publish critical path (hist-only); hhist is one
//      lane-0 uint2 store.
//      Kept (verified): gates-per-lane + DPP reduce, polls-before-xp
//      ordering, epoch-salted tags, bailout.
//   4. gemm_f16<1>: out = h_hist @ fc_W^T + fc_b
// ---------------------------------------------------------------------------

typedef __fp16 h2 __attribute__((ext_vector_type(2)));
typedef __fp16 h8 __attribute__((ext_vector_type(8)));
typedef float f4 __attribute__((ext_vector_type(4)));
typedef unsigned long long u64;

#define T_LEN 2048

static __device__ __forceinline__ unsigned int packh2(float a, float b) {
  h2 r = __builtin_amdgcn_cvt_pkrtz(a, b);
  return __builtin_bit_cast(unsigned int, r);
}
static __device__ __forceinline__ float fdot2u(unsigned int a, unsigned int b, float c) {
  return __builtin_amdgcn_fdot2(__builtin_bit_cast(h2, a), __builtin_bit_cast(h2, b), c, false);
}
static __device__ __forceinline__ float sigmoidf_(float x) {
  return 1.f / (1.f + __expf(-x));
}
static __device__ __forceinline__ float tanhf_(float x) {
  float e = __expf(-2.f * fabsf(x));
  float r = (1.f - e) / (1.f + e);
  return copysignf(r, x);
}
static __device__ __forceinline__ u64 aload(const u64* p) {
  return __hip_atomic_load(p, __ATOMIC_RELAXED, __HIP_MEMORY_SCOPE_AGENT);
}

// 16-lane (DPP-row) sum reduction: xor1, xor2 (quad_perm), row_half_mirror,
// row_mirror. All 16 lanes of the row end with the row sum. (R7/R10-verified.)
#define DPP_ADD1(v, CTRL)                                                      \
  v += __builtin_bit_cast(                                                     \
      float, __builtin_amdgcn_update_dpp(0, __builtin_bit_cast(int, v), CTRL,  \
                                         0xf, 0xf, true))
#define DPP_ROUND(CTRL)                                                        \
  DPP_ADD1(acc0, CTRL);                                                        \
  DPP_ADD1(acc1, CTRL);                                                        \
  DPP_ADD1(acc2, CTRL);                                                        \
  DPP_ADD1(acc3, CTRL)

// ---------------------------------------------------------------------------
__global__ void convert_all(const float* __restrict__ x, const float* __restrict__ wf,
                            const float* __restrict__ wb, const float* __restrict__ fcw,
                            _Float16* __restrict__ xf, _Float16* __restrict__ wff,
                            _Float16* __restrict__ wbf, _Float16* __restrict__ fcwf) {
  const size_t SX = 2097152, SW = 4194304, SFC = 2097152;
  size_t i = (size_t)blockIdx.x * 256 + threadIdx.x;
  if (i < SX) {
    xf[i] = (_Float16)x[i];
  } else if (i < SX + SW) {
    size_t j = i - SX; wff[j] = (_Float16)wf[j];
  } else if (i < SX + 2 * SW) {
    size_t j = i - SX - SW; wbf[j] = (_Float16)wb[j];
  } else if (i < SX + 2 * SW + SFC) {
    size_t j = i - SX - 2 * SW;
    int row = (int)(j >> 11), col = (int)(j & 2047);
    fcwf[j] = (row < 1000) ? (_Float16)fcw[(size_t)row * 2048 + col] : (_Float16)0.f;
  }
}

// epoch bump + seed gen-0 tags (payload h=0, tag=epoch<<12).
__global__ void init_state(u64* __restrict__ hc, unsigned* __restrict__ ep) {
  __shared__ unsigned sbs;
  if (threadIdx.x == 0) sbs = atomicAdd(ep, 1u) << 12;
  __syncthreads();
  u64 v = (u64)sbs;
  for (int i = threadIdx.x; i < 2048; i += 256)
    __hip_atomic_store(&hc[i], v, __ATOMIC_RELAXED, __HIP_MEMORY_SCOPE_AGENT);
}

// ---------------------------------------------------------------------------
// f16 GEMM, 128x128 tile, BK=64 (unchanged — verified R2/R3/R4)
// ---------------------------------------------------------------------------
#define LSTR 80

template <int MODE>
__global__ __launch_bounds__(256, 2) void gemm_f16(
    const _Float16* __restrict__ A, const _Float16* __restrict__ B,
    const float* __restrict__ bias1, const float* __restrict__ bias2,
    void* __restrict__ Cout, int M, int N, int K, int nout, int rev) {
  __shared__ _Float16 As[128 * LSTR];
  __shared__ _Float16 Bs[128 * LSTR];

  const int tid = threadIdx.x;
  const int ntn = N >> 7;
  const int tm = blockIdx.x / ntn, tn = blockIdx.x % ntn;
  const int wid = tid >> 6, lane = tid & 63;
  const int wr = wid >> 1, wc = wid & 1;
  const int quad = lane >> 4, l16 = lane & 15;

  const int srow = tid >> 1, seg = tid & 1;
  const int arow = rev ? (M - 1 - (tm * 128 + srow)) : (tm * 128 + srow);
  const int brow = tn * 128 + srow;

  f4 acc[4][4];
#pragma unroll
  for (int i = 0; i < 4; ++i)
#pragma unroll
    for (int j = 0; j < 4; ++j) acc[i][j] = (f4)0.f;

  for (int k0 = 0; k0 < K; k0 += 64) {
    uint4 va[4], vb[4];
    const uint4* gpa = (const uint4*)(A + (size_t)arow * K + k0 + seg * 32);
    const uint4* gpb = (const uint4*)(B + (size_t)brow * K + k0 + seg * 32);
#pragma unroll
    for (int c = 0; c < 4; ++c) va[c] = gpa[c];
#pragma unroll
    for (int c = 0; c < 4; ++c) vb[c] = gpb[c];

    __syncthreads();
    uint4* lpa = (uint4*)&As[srow * LSTR + seg * 32];
    uint4* lpb = (uint4*)&Bs[srow * LSTR + seg * 32];
#pragma unroll
    for (int c = 0; c < 4; ++c) lpa[c] = va[c];
#pragma unroll
    for (int c = 0; c < 4; ++c) lpb[c] = vb[c];
    __syncthreads();

#pragma unroll
    for (int kk = 0; kk < 64; kk += 32) {
      h8 af[4], bf[4];
#pragma unroll
      for (int i = 0; i < 4; ++i) {
        int m = wr * 64 + i * 16 + l16;
        af[i] = *(const h8*)&As[m * LSTR + kk + quad * 8];
        int n = wc * 64 + i * 16 + l16;
        bf[i] = *(const h8*)&Bs[n * LSTR + kk + quad * 8];
      }
#pragma unroll
      for (int i = 0; i < 4; ++i)
#pragma unroll
        for (int j = 0; j < 4; ++j)
          acc[i][j] = __builtin_amdgcn_mfma_f32_16x16x32_f16(af[i], bf[j], acc[i][j], 0, 0, 0);
    }
  }

  const int cm0 = tm * 128 + wr * 64, cn0 = tn * 128 + wc * 64;
#pragma unroll
  for (int i = 0; i < 4; ++i) {
#pragma unroll
    for (int j = 0; j < 4; ++j) {
      int n = cn0 + j * 16 + l16;
#pragma unroll
      for (int r = 0; r < 4; ++r) {
        int m = cm0 + i * 16 + quad * 4 + r;
        float v = acc[i][j][r];
        if (MODE == 0) {
          v += bias1[n] + bias2[n];
          ((_Float16*)Cout)[(size_t)m * N + n] = (_Float16)v;
        } else {
          if (n < nout) ((float*)Cout)[(size_t)m * nout + n] = v + bias1[n];
        }
      }
    }
  }
}

// ---------------------------------------------------------------------------
// Persistent BiLSTM recurrence, R13 (= R10 + publish-lane split).
// 128 blocks x 256 thr (4 waves), 1 block/CU. blk<64 fwd else bwd. Block
// owns 16 units j0..j0+15 = 64 W_hh rows = one 64B hc line. Wave wv owns
// units 4wv+rr (rr=lane>>4); lane computes the 4 GATE dots of its unit over
// k-slice kq*64..+63 (kq=lane&15). DPP 16-lane reduce.
// hc: [buf][dir][512] u64; word w = [h2(h[2w],h[2w+1]) | tag32],
// tag=(epoch<<12)+gen. Publish: lanes 0 AND 32 of each wave atomicExch the
// wave's 2 words in ONE instruction (pk is correct on both lanes after one
// shfl_xor(16)); the shfl_xor(32) runs after, feeding only the off-path
// hhist uint2 store. Consumer poll: R5/R10 single-issue atomic loop.
// 2-buffer safety: reaching t+2 data-depends on having consumed t+1.
// ---------------------------------------------------------------------------
__global__ __launch_bounds__(256, 1) void lstm_rec(
    const float* __restrict__ Whh_f, const float* __restrict__ Whh_b,
    const _Float16* __restrict__ xp,   // [2][2048][4096]
    u64* __restrict__ hc,              // [2][2][512] agent-scope
    unsigned* __restrict__ ep,         // epoch counter (post-incremented)
    _Float16* __restrict__ hhist) {    // [2048][2048]
  const int tid = threadIdx.x;
  const int blk = blockIdx.x;
  const int dir = blk >> 6;
  const int ib = blk & 63;
  const int j0 = ib * 16;
  const int wv = tid >> 6;
  const int l = tid & 63;
  const int rr = l >> 4;     // unit replica 0..3 (DPP row)
  const int kq = l & 15;     // 16 k-slices of 64
  const int wrow_u = j0 + 4 * wv + rr;  // unit index within [0,1024)

  const unsigned SB =
      (__hip_atomic_load(ep, __ATOMIC_RELAXED, __HIP_MEMORY_SCOPE_AGENT) - 1u) << 12;

  const float* Whh = dir ? Whh_b : Whh_f;
  const _Float16* xpd = xp + (size_t)dir * (2048u * 4096u);

  __shared__ unsigned int lds_h[2][16 * 36];  // [buf][seg stride 36]

  // one-time: W_hh[g*1024 + wrow_u][kq*64 .. +63] -> f16 regs, g = gate 0..3
  unsigned int w[4][32];
#pragma unroll
  for (int g = 0; g < 4; ++g) {
    const float* wp = Whh + (size_t)(g * 1024 + wrow_u) * 1024 + kq * 64;
#pragma unroll
    for (int i = 0; i < 16; ++i) {
      float4 v = ((const float4*)wp)[i];
      w[g][2 * i] = packh2(v.x, v.y);
      w[g][2 * i + 1] = packh2(v.z, v.w);
    }
  }

  float c = 0.f;  // cell state for unit wrow_u (replicated across 16 lanes)

  // x_proj for t=0: 4 gate preacts of unit wrow_u (stride-1024 scalars)
  float xf0, xf1, xf2, xf3;
  {
    const _Float16* xr = xpd + wrow_u;
    xf0 = (float)xr[0]; xf1 = (float)xr[1024];
    xf2 = (float)xr[2048]; xf3 = (float)xr[3072];
  }

  for (int t = 0; t < T_LEN; ++t) {
    const int buf = t & 1;
    const unsigned exp0 = SB + (unsigned)t;

    // ---- poll own 2 words (2tid, 2tid+1) ----
    // Issue the poll loads FIRST, then the xp prefetch: the first check
    // then needs only the polls (oldest in the FIFO) while the 4 slow xp
    // loads drain under the detection wait.
    const u64* src = hc + (((size_t)buf * 2 + dir) * 512 + 2 * tid);
    u64 a = aload(&src[0]);
    u64 b = aload(&src[1]);

    int tnx = (t + 1 < T_LEN) ? t + 1 : t;
    const _Float16* xr = xpd + (size_t)tnx * 4096 + wrow_u;
    _Float16 n0 = xr[0], n1 = xr[1024], n2 = xr[2048], n3 = xr[3072];

    unsigned d0, d1;
    {
      int cnt = 0;
      while ((unsigned)a != exp0 || (unsigned)b != exp0) {
        if (++cnt > (1 << 12)) break;  // bailout: fail absmax, never hang
        a = aload(&src[0]);
        b = aload(&src[1]);
      }
      d0 = (unsigned)(a >> 32);
      d1 = (unsigned)(b >> 32);
    }

    // stage h payload: dwords 2tid,2tid+1 -> seg tid>>4, offset 2*(tid&15)
    *(uint2*)&lds_h[buf][(tid >> 4) * 36 + 2 * (tid & 15)] = make_uint2(d0, d1);
    __syncthreads();  // single barrier per step (double-buffered LDS)

    // ---- dot: 4 gates x 64-elem slice; 8 ds_read_b128, 128 fdot2 ----
    float acc0 = 0.f, acc1 = 0.f, acc2 = 0.f, acc3 = 0.f;
    const uint4* hp = (const uint4*)&lds_h[buf][kq * 36];
#pragma unroll
    for (int i = 0; i < 8; ++i) {
      uint4 hv = hp[i];
      acc0 = fdot2u(w[0][4 * i + 0], hv.x, acc0);
      acc0 = fdot2u(w[0][4 * i + 1], hv.y, acc0);
      acc0 = fdot2u(w[0][4 * i + 2], hv.z, acc0);
      acc0 = fdot2u(w[0][4 * i + 3], hv.w, acc0);
      acc1 = fdot2u(w[1][4 * i + 0], hv.x, acc1);
      acc1 = fdot2u(w[1][4 * i + 1], hv.y, acc1);
      acc1 = fdot2u(w[1][4 * i + 2], hv.z, acc1);
      acc1 = fdot2u(w[1][4 * i + 3], hv.w, acc1);
      acc2 = fdot2u(w[2][4 * i + 0], hv.x, acc2);
      acc2 = fdot2u(w[2][4 * i + 1], hv.y, acc2);
      acc2 = fdot2u(w[2][4 * i + 2], hv.z, acc2);
      acc2 = fdot2u(w[2][4 * i + 3], hv.w, acc2);
      acc3 = fdot2u(w[3][4 * i + 0], hv.x, acc3);
      acc3 = fdot2u(w[3][4 * i + 1], hv.y, acc3);
      acc3 = fdot2u(w[3][4 * i + 2], hv.z, acc3);
      acc3 = fdot2u(w[3][4 * i + 3], hv.w, acc3);
    }
    // 16-lane reduce via DPP (VALU-only): xor1, xor2, 8-mirror, 16-mirror
    DPP_ROUND(0xB1);   // quad_perm {1,0,3,2}
    DPP_ROUND(0x4E);   // quad_perm {2,3,0,1}
    DPP_ROUND(0x141);  // row_half_mirror
    DPP_ROUND(0x140);  // row_mirror

    // lane now holds all 4 gate preacts of unit wrow_u directly
    float ii = sigmoidf_(acc0 + xf0);
    float ff = sigmoidf_(acc1 + xf1);
    float g_ = tanhf_(acc2 + xf2);
    float oo = sigmoidf_(acc3 + xf3);
    c = ff * c + ii * g_;
    float h = oo * tanhf_(c);  // replicated over 16 lanes of row rr

    // one shuffle to pair rows: lanes rr=0 hold (h0,h1), lanes rr=2 (h2,h3)
    float hx = __shfl_xor(h, 16, 64);   // rows 0<->1, rows 2<->3
    unsigned pk = packh2(h, hx);

    const unsigned tg = SB + (unsigned)(t + 1);
    const int slot = (t + 1) & 1;
    // publish: lanes 0 and 32 exchange the wave's 2 words in ONE wave
    // instruction (R10-verified protocol; shfl_xor(32) moved off-path).
    if ((l & 31) == 0) {
      u64 v = ((u64)pk << 32) | tg;
      u64* dst = hc + (((size_t)slot * 2 + dir) * 512 +
                       (size_t)(ib * 8 + 2 * wv + (l >> 5)));
      (void)__hip_atomic_exchange(dst, v, __ATOMIC_RELAXED,
                                  __HIP_MEMORY_SCOPE_AGENT);
    }
    // off the critical sync path: gather (h2,h3) to lane0, one uint2 store
    unsigned pko = (unsigned)__shfl_xor((int)pk, 32, 64);
    if (l == 0) {
      int tout = dir ? (T_LEN - 1 - t) : t;
      *(uint2*)&hhist[(size_t)tout * 2048 + (size_t)(dir * 1024 + j0 + 4 * wv)] =
          make_uint2(pk, pko);
    }

    // convert next-step xp (prefetched above)
    xf0 = (float)n0; xf1 = (float)n1; xf2 = (float)n2; xf3 = (float)n3;
  }
}

// ---------------------------------------------------------------------------
extern "C" void kernel_launch(void* const* d_in, const int* in_sizes, int n_in,
                              void* d_out, int out_size, void* d_ws, size_t ws_size,
                              hipStream_t stream) {
  (void)in_sizes; (void)n_in; (void)out_size; (void)ws_size;
  const float* x     = (const float*)d_in[0];
  const float* Wih_f = (const float*)d_in[1];
  const float* Whh_f = (const float*)d_in[2];
  const float* bih_f = (const float*)d_in[3];
  const float* bhh_f = (const float*)d_in[4];
  const float* Wih_b = (const float*)d_in[5];
  const float* Whh_b = (const float*)d_in[6];
  const float* bih_b = (const float*)d_in[7];
  const float* bhh_b = (const float*)d_in[8];
  const float* fcW   = (const float*)d_in[9];
  const float* fcb   = (const float*)d_in[10];

  char* ws = (char*)d_ws;
  _Float16* xf16   = (_Float16*)(ws + 0);
  _Float16* wih16f = (_Float16*)(ws + 4194304);
  _Float16* wih16b = (_Float16*)(ws + 12582912);
  _Float16* fcw16  = (_Float16*)(ws + 20971520);
  _Float16* xp16   = (_Float16*)(ws + 25165824);   // [2][2048][4096]
  _Float16* hhist  = (_Float16*)(ws + 58720256);   // [2048][2048]
  u64*      hc     = (u64*)     (ws + 67108864);   // [2][2][512]
  unsigned* epoch  = (unsigned*)(ws + 67141632);   // epoch counter

  const size_t SX = 2097152, SW = 4194304, SFC = 2097152;
  const size_t total_cvt = SX + 2 * SW + SFC;

  convert_all<<<dim3((unsigned)((total_cvt + 255) / 256)), 256, 0, stream>>>(
      x, Wih_f, Wih_b, fcW, xf16, wih16f, wih16b, fcw16);
  init_state<<<1, 256, 0, stream>>>(hc, epoch);

  gemm_f16<0><<<dim3(512), 256, 0, stream>>>(xf16, wih16f, bih_f, bhh_f,
                                             (void*)xp16, 2048, 4096, 1024, 4096, 0);
  gemm_f16<0><<<dim3(512), 256, 0, stream>>>(xf16, wih16b, bih_b, bhh_b,
                                             (void*)(xp16 + (size_t)2048 * 4096),
                                             2048, 4096, 1024, 4096, 1);

  lstm_rec<<<dim3(128), 256, 0, stream>>>(Whh_f, Whh_b, xp16, hc, epoch, hhist);

  gemm_f16<1><<<dim3(128), 256, 0, stream>>>(hhist, fcw16, fcb, nullptr,
                                             d_out, 2048, 1024, 2048, 1000, 0);
}